// Round 8
// baseline (226.188 us; speedup 1.0000x reference)
//
#include <hip/hip_runtime.h>
#include <math.h>

#define P 128
#define T_WIN 480
#define STEPD 20
#define LAG_W 24
#define NITER 16
#define SEG 128
#define NCHUNK 32   // chunks per segment; 512 elements (4 rows) per chunk

// wbuf layout (floats, 2048 total):
// [0..479]=w_norm  [480..959]=sqrt(w_norm)  [960]=denom  [961]=S
// [962..985]=coef_m=a^(20(23-m))  [986..1005]=sqrt(bw_d)=sqrt(a^(19-d))
// [1024..1174]=pw20[x]=a^(20x), x=0..150   [1280..1407]=ainvt[k]=a^(-20k), k=0..127
#define SBW_OFF 986
#define PW20_OFF 1024
#define AINVT_OFF 1280

// ---------------- kernel 0: EWMA weights (fp64, one block) ----------------
__global__ __launch_bounds__(512) void weights_kernel(const float* __restrict__ a,
                                                      float* __restrict__ wbuf) {
  __shared__ double redd[512];
  const int t = threadIdx.x;
  const double la = log((double)a[0]);
  const double u = (t < T_WIN) ? exp((double)(T_WIN - 1 - t) * la) : 0.0;
  redd[t] = u;
  __syncthreads();
  for (int off = 256; off > 0; off >>= 1) {
    if (t < off) redd[t] += redd[t + off];
    __syncthreads();
  }
  const double S = redd[0];
  __syncthreads();
  redd[t] = u * u;
  __syncthreads();
  for (int off = 256; off > 0; off >>= 1) {
    if (t < off) redd[t] += redd[t + off];
    __syncthreads();
  }
  const double Su2 = redd[0];
  if (t < T_WIN) {
    const double wn = u / S * (double)T_WIN;
    wbuf[t] = (float)wn;
    wbuf[T_WIN + t] = (float)sqrt(wn);
  }
  if (t == 0) {
    wbuf[960] = (float)(1.0 - Su2 / (S * S));
    wbuf[961] = (float)S;
  }
  if (t < LAG_W) wbuf[962 + t] = (float)exp((double)(STEPD * (LAG_W - 1 - t)) * la);
  if (t < STEPD) wbuf[SBW_OFF + t] = (float)exp(0.5 * (double)(STEPD - 1 - t) * la);
  if (t < 151) wbuf[PW20_OFF + t] = (float)exp((double)(20 * t) * la);
  if (t < SEG) wbuf[AINVT_OFF + t] = (float)exp(-(double)(20 * t) * la);
}

// ---------------- kernel 1: FUSED C-compute + segmented prefix scan ----------------
// Block (seg, chunk) owns 512 G-elements (4 rows). For k=0..SEG-1: stage Y block
// (scaled by sqrt(bw_d)) to LDS, compute C elements on the fly, accumulate
// G[k] = sum_{i<=k} a^(-20 i) C_i in registers, write G. chunk 0 also emits cvec.
__global__ __launch_bounds__(256) void fused_cg_kernel(const float* __restrict__ Y,
                                                       const float* __restrict__ wbuf,
                                                       float* __restrict__ cvec,
                                                       float* __restrict__ Gall,
                                                       int nseg) {
  const int bid = blockIdx.x;
  int seg, chunk;
  if (nseg == 8) { seg = bid & 7; chunk = bid >> 3; }   // same-seg -> same XCD
  else { seg = bid / NCHUNK; chunk = bid - seg * NCHUNK; }
  const int tid = threadIdx.x;

  __shared__ float ysm[STEPD][P];      // 10 KB staged Y block (sqrt(bw)-scaled)
  __shared__ float sbwsm[STEPD];
  __shared__ float ainvsm[SEG];

  if (tid < STEPD) sbwsm[tid] = wbuf[SBW_OFF + tid];
  if (tid < SEG) ainvsm[tid] = wbuf[AINVT_OFF + tid];

  const int elem0 = chunk * 512 + tid * 2;   // two consecutive cols, same row
  const int r = elem0 >> 7;
  const int c0 = elem0 & 127;
  float g0 = 0.0f, g1 = 0.0f;

  for (int k = 0; k < SEG; ++k) {
    const int kb = seg * SEG + k;
    __syncthreads();
    // stage Y block kb: 640 float4
    const float4* __restrict__ Yb4 = (const float4*)(Y + (size_t)kb * STEPD * P);
    for (int i = tid; i < STEPD * P / 4; i += 256) {
      float4 v = Yb4[i];
      const float sw = sbwsm[i >> 5];
      v.x *= sw; v.y *= sw; v.z *= sw; v.w *= sw;
      ((float4*)&ysm[0][0])[i] = v;
    }
    __syncthreads();
    // C elements: s0 = sum_d y[d][r]*y[d][c0], s1 = ... c0+1
    float s0 = 0.0f, s1 = 0.0f;
#pragma unroll
    for (int d = 0; d < STEPD; ++d) {
      const float yr = ysm[d][r];
      s0 = fmaf(yr, ysm[d][c0], s0);
      s1 = fmaf(yr, ysm[d][c0 + 1], s1);
    }
    const float av = ainvsm[k];
    g0 = fmaf(av, s0, g0);
    g1 = fmaf(av, s1, g1);
    float2 o; o.x = g0; o.y = g1;
    *(float2*)(Gall + (size_t)kb * (P * P) + elem0) = o;
    // cvec from chunk-0 blocks: cvec[kb][col] = sum_d bw_d * y = sum_d sbw*ysm
    if (chunk == 0 && tid < P) {
      float s = 0.0f;
#pragma unroll
      for (int d = 0; d < STEPD; ++d) s = fmaf(sbwsm[d], ysm[d][tid], s);
      cvec[(size_t)kb * P + tid] = s;
    }
  }
}

// ---------------- kernel 2: TWO windows per block; batched G loads; dual CG ----------------
__global__ __launch_bounds__(256, 2) void window7_kernel(
    const float* __restrict__ Y, const float* __restrict__ wbuf,
    const float* __restrict__ logridge, const float* __restrict__ cvec,
    const float* __restrict__ Gall, float* __restrict__ e_all,
    float* __restrict__ s_all, int W, int nb) {
  const int bid = blockIdx.x;
  const int q = nb >> 3, rr8 = nb & 7;
  const int xcd = bid & 7, idx = bid >> 3;
  const int wg = ((xcd < rr8) ? (xcd * (q + 1)) : (rr8 * (q + 1) + (xcd - rr8) * q)) + idx;
  const int jA = 2 * wg;
  const int jB = (jA + 1 < W) ? (jA + 1) : jA;

  const int tid = threadIdx.x;
  const int ti = tid >> 4, tj = tid & 15;
  const int lane = tid & 63;
  const int wv = tid >> 6;

  __shared__ float psmA[P], psmB[P];
  __shared__ float ApsmA[P], ApsmB[P];
  __shared__ float vsmA[P], vsmB[P];
  __shared__ float meansmA[P], meansmB[P];
  __shared__ float coefsm[LAG_W];
  __shared__ float pap_waveA[4], pap_waveB[4];
  __shared__ float rs_waveA[4], rs_waveB[4];
  __shared__ float retdA[STEPD], retdB[STEPD];

  if (tid < LAG_W) coefsm[tid] = wbuf[962 + tid];
  __syncthreads();

  const float S = wbuf[961];
  const float denom = wbuf[960];
  const float ridge = expf(logridge[0]);

  int rowi[8], rowoff[8];
#pragma unroll
  for (int u = 0; u < 8; ++u) {
    rowi[u] = (u < 4) ? (ti * 4 + u) : (64 + ti * 4 + u - 4);
    rowoff[u] = rowi[u] * P + tj * 4;
  }

  // ---- G-difference plans ----
  int matsA[3], matsB[3];
  float sclsA[3], sclsB[3];
  int nmA = 0, nmB = 0;
  {
    const int o1 = jA & ~(SEG - 1);
    const int end = jA + 23;
    const int b = o1 + SEG;
    const float pA = wbuf[PW20_OFF + (end - o1)];
    if (end < b) {
      matsA[nmA] = end; sclsA[nmA] = pA; ++nmA;
      if (jA > o1) { matsA[nmA] = jA - 1; sclsA[nmA] = -pA; ++nmA; }
    } else {
      const float pB2 = wbuf[PW20_OFF + (end - b)];
      matsA[nmA] = b - 1; sclsA[nmA] = pA; ++nmA;
      if (jA > o1) { matsA[nmA] = jA - 1; sclsA[nmA] = -pA; ++nmA; }
      matsA[nmA] = end; sclsA[nmA] = pB2; ++nmA;
    }
  }
  {
    const int o1 = jB & ~(SEG - 1);
    const int end = jB + 23;
    const int b = o1 + SEG;
    const float pA = wbuf[PW20_OFF + (end - o1)];
    if (end < b) {
      matsB[nmB] = end; sclsB[nmB] = pA; ++nmB;
      if (jB > o1) { matsB[nmB] = jB - 1; sclsB[nmB] = -pA; ++nmB; }
    } else {
      const float pB2 = wbuf[PW20_OFF + (end - b)];
      matsB[nmB] = b - 1; sclsB[nmB] = pA; ++nmB;
      if (jB > o1) { matsB[nmB] = jB - 1; sclsB[nmB] = -pA; ++nmB; }
      matsB[nmB] = end; sclsB[nmB] = pB2; ++nmB;
    }
  }

  float accA[8][8], accB[8][8];
#pragma unroll
  for (int u = 0; u < 8; ++u)
#pragma unroll
    for (int v = 0; v < 8; ++v) { accA[u][v] = 0.0f; accB[u][v] = 0.0f; }

  // batched dual-stream accumulate: 16 float4 in flight per half
  auto accum_pair = [&](const float* __restrict__ GmA, float cfA,
                        const float* __restrict__ GmB, float cfB) {
#pragma unroll
    for (int h = 0; h < 2; ++h) {
      float4 ta[8], tb[8];
#pragma unroll
      for (int u = 0; u < 4; ++u) {
        const int uu = h * 4 + u;
        ta[2 * u]     = *(const float4*)(GmA + rowoff[uu]);
        ta[2 * u + 1] = *(const float4*)(GmA + rowoff[uu] + 64);
        tb[2 * u]     = *(const float4*)(GmB + rowoff[uu]);
        tb[2 * u + 1] = *(const float4*)(GmB + rowoff[uu] + 64);
      }
#pragma unroll
      for (int u = 0; u < 4; ++u) {
        const int uu = h * 4 + u;
        accA[uu][0] += cfA * ta[2*u].x;   accA[uu][1] += cfA * ta[2*u].y;
        accA[uu][2] += cfA * ta[2*u].z;   accA[uu][3] += cfA * ta[2*u].w;
        accA[uu][4] += cfA * ta[2*u+1].x; accA[uu][5] += cfA * ta[2*u+1].y;
        accA[uu][6] += cfA * ta[2*u+1].z; accA[uu][7] += cfA * ta[2*u+1].w;
        accB[uu][0] += cfB * tb[2*u].x;   accB[uu][1] += cfB * tb[2*u].y;
        accB[uu][2] += cfB * tb[2*u].z;   accB[uu][3] += cfB * tb[2*u].w;
        accB[uu][4] += cfB * tb[2*u+1].x; accB[uu][5] += cfB * tb[2*u+1].y;
        accB[uu][6] += cfB * tb[2*u+1].z; accB[uu][7] += cfB * tb[2*u+1].w;
      }
    }
  };
  auto accum_one = [&](const float* __restrict__ Gm, float cf, float (*acc)[8]) {
#pragma unroll
    for (int h = 0; h < 2; ++h) {
      float4 ta[8];
#pragma unroll
      for (int u = 0; u < 4; ++u) {
        const int uu = h * 4 + u;
        ta[2 * u]     = *(const float4*)(Gm + rowoff[uu]);
        ta[2 * u + 1] = *(const float4*)(Gm + rowoff[uu] + 64);
      }
#pragma unroll
      for (int u = 0; u < 4; ++u) {
        const int uu = h * 4 + u;
        acc[uu][0] += cf * ta[2*u].x;   acc[uu][1] += cf * ta[2*u].y;
        acc[uu][2] += cf * ta[2*u].z;   acc[uu][3] += cf * ta[2*u].w;
        acc[uu][4] += cf * ta[2*u+1].x; acc[uu][5] += cf * ta[2*u+1].y;
        acc[uu][6] += cf * ta[2*u+1].z; acc[uu][7] += cf * ta[2*u+1].w;
      }
    }
  };

  accum_pair(Gall + (size_t)matsA[0] * (P * P), sclsA[0],
             Gall + (size_t)matsB[0] * (P * P), sclsB[0]);
  for (int m = 1; m < 3; ++m) {
    const bool dA = m < nmA, dB = m < nmB;
    if (dA && dB)
      accum_pair(Gall + (size_t)matsA[m] * (P * P), sclsA[m],
                 Gall + (size_t)matsB[m] * (P * P), sclsB[m]);
    else if (dA)
      accum_one(Gall + (size_t)matsA[m] * (P * P), sclsA[m], accA);
    else if (dB)
      accum_one(Gall + (size_t)matsB[m] * (P * P), sclsB[m], accB);
  }

  // ---- mraw for both windows ----
  if (tid < P) {
    float s = 0.0f;
    for (int m = 0; m < LAG_W; ++m) s += coefsm[m] * cvec[(size_t)(jA + m) * P + tid];
    meansmA[tid] = s;
  } else {
    const int t2 = tid - P;
    float s = 0.0f;
    for (int m = 0; m < LAG_W; ++m) s += coefsm[m] * cvec[(size_t)(jB + m) * P + t2];
    meansmB[t2] = s;
  }
  if (tid < P) { psmA[tid] = 1.0f; psmB[tid] = 1.0f; }
  __syncthreads();

  // ---- M (registers) ----
  {
    const float sc1 = 1.0f / (S * denom);
    const float sc2 = 1.0f / (S * S * denom);
#pragma unroll
    for (int u = 0; u < 8; ++u) {
      const int rr = rowi[u];
      const float mrA = meansmA[rr] * sc2;
      const float mrB = meansmB[rr] * sc2;
#pragma unroll
      for (int v = 0; v < 8; ++v) {
        const int c = (v < 4) ? (tj * 4 + v) : (64 + tj * 4 + (v - 4));
        float mA = accA[u][v] * sc1 - mrA * meansmA[c];
        float mB = accB[u][v] * sc1 - mrB * meansmB[c];
        if (rr == c) { mA += ridge; mB += ridge; }
        accA[u][v] = mA;
        accB[u][v] = mB;
      }
    }
  }

  // ---- dual CG ----
  float xoA = 0.0f, roA = 1.0f, poA = 1.0f, rsA = (float)P;
  float xoB = 0.0f, roB = 1.0f, poB = 1.0f, rsB = (float)P;

  for (int it = 0; it < NITER; ++it) {
    const float4 a0 = *(const float4*)&psmA[tj * 4];
    const float4 a1 = *(const float4*)&psmA[64 + tj * 4];
    const float4 b0 = *(const float4*)&psmB[tj * 4];
    const float4 b1 = *(const float4*)&psmB[64 + tj * 4];
    float pvA[8] = {a0.x, a0.y, a0.z, a0.w, a1.x, a1.y, a1.z, a1.w};
    float pvB[8] = {b0.x, b0.y, b0.z, b0.w, b1.x, b1.y, b1.z, b1.w};
    float apA[8], apB[8];
#pragma unroll
    for (int u = 0; u < 8; ++u) {
      float sA = 0.0f, sB = 0.0f;
#pragma unroll
      for (int v = 0; v < 8; ++v) { sA += accA[u][v] * pvA[v]; sB += accB[u][v] * pvB[v]; }
      apA[u] = sA; apB[u] = sB;
    }
#pragma unroll
    for (int m = 1; m <= 8; m <<= 1) {
#pragma unroll
      for (int u = 0; u < 8; ++u) {
        apA[u] += __shfl_xor(apA[u], m);
        apB[u] += __shfl_xor(apB[u], m);
      }
    }
    if (tj == 0) {
      float papA = 0.0f, papB = 0.0f;
#pragma unroll
      for (int u = 0; u < 8; ++u) {
        ApsmA[rowi[u]] = apA[u]; papA += apA[u] * psmA[rowi[u]];
        ApsmB[rowi[u]] = apB[u]; papB += apB[u] * psmB[rowi[u]];
      }
      papA += __shfl_down(papA, 16); papB += __shfl_down(papB, 16);
      papA += __shfl_down(papA, 32); papB += __shfl_down(papB, 32);
      if (lane == 0) { pap_waveA[wv] = papA; pap_waveB[wv] = papB; }
    }
    __syncthreads();  // B1

    const float papAt = pap_waveA[0] + pap_waveA[1] + pap_waveA[2] + pap_waveA[3];
    const float papBt = pap_waveB[0] + pap_waveB[1] + pap_waveB[2] + pap_waveB[3];
    const float alA = rsA / papAt;
    const float alB = rsB / papBt;
    float rspA = 0.0f, rspB = 0.0f;
    if (tid < P) {
      xoA += alA * poA; roA -= alA * ApsmA[tid]; rspA = roA * roA;
      xoB += alB * poB; roB -= alB * ApsmB[tid]; rspB = roB * roB;
    }
#pragma unroll
    for (int m = 32; m > 0; m >>= 1) {
      rspA += __shfl_down(rspA, m);
      rspB += __shfl_down(rspB, m);
    }
    if (lane == 0) { rs_waveA[wv] = rspA; rs_waveB[wv] = rspB; }
    __syncthreads();  // B2

    const float rsnA = rs_waveA[0] + rs_waveA[1] + rs_waveA[2] + rs_waveA[3];
    const float rsnB = rs_waveB[0] + rs_waveB[1] + rs_waveB[2] + rs_waveB[3];
    const float beA = rsnA / rsA;
    const float beB = rsnB / rsB;
    rsA = rsnA; rsB = rsnB;
    if (tid < P) {
      poA = roA + beA * poA; psmA[tid] = poA;
      poB = roB + beB * poB; psmB[tid] = poB;
    }
    __syncthreads();  // B3
  }

  // ---- publish v, sum(v) ----
  float svA = 0.0f, svB = 0.0f;
  if (tid < P) {
    vsmA[tid] = xoA; vsmB[tid] = xoB;
    svA = xoA; svB = xoB;
  }
#pragma unroll
  for (int m = 32; m > 0; m >>= 1) {
    svA += __shfl_down(svA, m);
    svB += __shfl_down(svB, m);
  }
  if (lane == 0) { rs_waveA[wv] = svA; rs_waveB[wv] = svB; }
  __syncthreads();
  const float sumvA = rs_waveA[0] + rs_waveA[1] + rs_waveA[2] + rs_waveA[3];
  const float sumvB = rs_waveB[0] + rs_waveB[1] + rs_waveB[2] + rs_waveB[3];

  // ---- test returns ----
  const float* __restrict__ YteA = Y + (size_t)(jA + LAG_W) * STEPD * P;
  const float* __restrict__ YteB = Y + (size_t)(jB + LAG_W) * STEPD * P;
  for (int d = wv; d < STEPD; d += 4) {
    float pA = YteA[(size_t)d * P + lane] * vsmA[lane] +
               YteA[(size_t)d * P + 64 + lane] * vsmA[64 + lane];
    float pB = YteB[(size_t)d * P + lane] * vsmB[lane] +
               YteB[(size_t)d * P + 64 + lane] * vsmB[64 + lane];
    for (int off = 32; off > 0; off >>= 1) {
      pA += __shfl_down(pA, off);
      pB += __shfl_down(pB, off);
    }
    if (lane == 0) { retdA[d] = pA; retdB[d] = pB; }
  }
  __syncthreads();

  if (tid == 0) {
    const float invs = 1.0f / sumvA;
    float e = 0.0f, s = 0.0f;
#pragma unroll
    for (int d = 0; d < STEPD; ++d) {
      const float rr = retdA[d] * invs;
      e += rr; s += rr * rr;
    }
    e_all[jA] = e;
    s_all[jA] = s * (1.0f / (float)STEPD);
  } else if (tid == 64) {
    const float invs = 1.0f / sumvB;
    float e = 0.0f, s = 0.0f;
#pragma unroll
    for (int d = 0; d < STEPD; ++d) {
      const float rr = retdB[d] * invs;
      e += rr; s += rr * rr;
    }
    e_all[jB] = e;
    s_all[jB] = s * (1.0f / (float)STEPD);
  }
}

// ---------------- fallback: per-window full recompute ----------------
__global__ __launch_bounds__(256, 2) void window_fallback(
    const float* __restrict__ Y, const float* __restrict__ wbuf,
    const float* __restrict__ logridge, float* __restrict__ e_all,
    float* __restrict__ s_all, int W) {
  const int j = blockIdx.x;
  const int tid = threadIdx.x;
  const int ti = tid >> 4;
  const int tj = tid & 15;

  __shared__ float Msm[P][P + 1];
  __shared__ float wsm[T_WIN];
  __shared__ float swsm[T_WIN];
  __shared__ float meansm[P];
  __shared__ float red[256];
  __shared__ float retd[STEPD];
  __shared__ float zsm[P];
  __shared__ float vsm[P];
  __shared__ float bsm[P];

  float* stage = &Msm[0][0];

  for (int t = tid; t < T_WIN; t += 256) {
    wsm[t] = wbuf[t];
    swsm[t] = wbuf[T_WIN + t];
  }
  if (tid < P) bsm[tid] = 1.0f;
  const float denom = wbuf[960];
  const float ridge = expf(logridge[0]);
  __syncthreads();

  const float* __restrict__ Ywin = Y + (size_t)j * STEPD * P;
  {
    const int col = tid & 127;
    const int half = tid >> 7;
    float m = 0.0f;
    const int t0 = half * (T_WIN / 2), t1 = t0 + T_WIN / 2;
    for (int t = t0; t < t1; ++t) m += wsm[t] * Ywin[(size_t)t * P + col];
    red[tid] = m;
    __syncthreads();
    if (tid < P) meansm[tid] = (red[tid] + red[tid + 128]) * (1.0f / (float)T_WIN);
    __syncthreads();
  }

  float acc[8][8];
#pragma unroll
  for (int u = 0; u < 8; ++u)
#pragma unroll
    for (int v = 0; v < 8; ++v) acc[u][v] = 0.0f;

  for (int c = 0; c < T_WIN / 32; ++c) {
    __syncthreads();
#pragma unroll
    for (int i = 0; i < 4; ++i) {
      const int idx = i * 1024 + tid * 4;
      float4 v = *(const float4*)(Ywin + (size_t)c * 32 * P + idx);
      const float sw = swsm[c * 32 + (idx >> 7)];
      v.x *= sw; v.y *= sw; v.z *= sw; v.w *= sw;
      *(float4*)(stage + idx) = v;
    }
    __syncthreads();
#pragma unroll 4
    for (int t = 0; t < 32; ++t) {
      const float* rowp = stage + t * P;
      float af[8], bf[8];
      *(float4*)(af) = *(const float4*)(rowp + ti * 8);
      *(float4*)(af + 4) = *(const float4*)(rowp + ti * 8 + 4);
      *(float4*)(bf) = *(const float4*)(rowp + tj * 8);
      *(float4*)(bf + 4) = *(const float4*)(rowp + tj * 8 + 4);
#pragma unroll
      for (int u = 0; u < 8; ++u)
#pragma unroll
        for (int v = 0; v < 8; ++v) acc[u][v] += af[u] * bf[v];
    }
  }
  __syncthreads();

  const float invTd = 1.0f / ((float)T_WIN * denom);
#pragma unroll
  for (int u = 0; u < 8; ++u) {
    const int r = ti * 8 + u;
    const float mr = meansm[r];
#pragma unroll
    for (int v = 0; v < 8; ++v) {
      const int cc = tj * 8 + v;
      float m = (acc[u][v] - (float)T_WIN * mr * meansm[cc]) * invTd;
      if (r == cc) m += ridge;
      Msm[r][cc] = m;
    }
  }
  __syncthreads();

  for (int k = 0; k < P; ++k) {
    const float dkk = Msm[k][k];
    const float sq = sqrtf(dkk);
    const float invd = 1.0f / sq;
    if (tid == 0) Msm[k][k] = sq;
    const int i = k + 1 + tid;
    if (i < P) Msm[i][k] *= invd;
    __syncthreads();
    const int nrem = P - 1 - k;
    for (int ii = ti; ii < nrem; ii += 16) {
      const int ri = k + 1 + ii;
      const float Lik = Msm[ri][k];
      for (int jj = tj; jj < nrem; jj += 16) {
        const int cj = k + 1 + jj;
        Msm[ri][cj] -= Lik * Msm[cj][k];
      }
    }
    __syncthreads();
  }

  for (int k = 0; k < P; ++k) {
    const float zk = bsm[k] / Msm[k][k];
    if (tid == 0) zsm[k] = zk;
    const int i = k + 1 + tid;
    if (i < P) bsm[i] -= Msm[i][k] * zk;
    __syncthreads();
  }
  for (int k = P - 1; k >= 0; --k) {
    const float vk = zsm[k] / Msm[k][k];
    if (tid == 0) vsm[k] = vk;
    if (tid < k) zsm[tid] -= Msm[k][tid] * vk;
    __syncthreads();
  }

  red[tid] = (tid < P) ? vsm[tid] : 0.0f;
  __syncthreads();
  for (int off = 128; off > 0; off >>= 1) {
    if (tid < off) red[tid] += red[tid + off];
    __syncthreads();
  }

  const float* __restrict__ Yte = Y + (size_t)(j + LAG_W) * STEPD * P;
  const int wv = tid >> 6;
  const int lane = tid & 63;
  for (int d = wv; d < STEPD; d += 4) {
    float pp = Yte[(size_t)d * P + lane] * vsm[lane] +
               Yte[(size_t)d * P + 64 + lane] * vsm[64 + lane];
    for (int off = 32; off > 0; off >>= 1) pp += __shfl_down(pp, off);
    if (lane == 0) retd[d] = pp;
  }
  __syncthreads();

  if (tid == 0) {
    const float invs = 1.0f / red[0];
    float e = 0.0f, s = 0.0f;
#pragma unroll
    for (int d = 0; d < STEPD; ++d) {
      const float r = retd[d] * invs;
      e += r;
      s += r * r;
    }
    e_all[j] = e;
    s_all[j] = s * (1.0f / (float)STEPD);
  }
}

// ---------------- kernel 3: final reduction ----------------
__global__ __launch_bounds__(256) void final_kernel(const float* __restrict__ e_all,
                                                    const float* __restrict__ s_all,
                                                    float* __restrict__ out, int W) {
  __shared__ float r1[256], r2[256];
  const int tid = threadIdx.x;
  float e = 0.0f, s = 0.0f;
  for (int i = tid; i < W; i += 256) {
    e += e_all[i];
    s += s_all[i];
  }
  r1[tid] = e;
  r2[tid] = s;
  __syncthreads();
  for (int off = 128; off > 0; off >>= 1) {
    if (tid < off) {
      r1[tid] += r1[tid + off];
      r2[tid] += r2[tid + off];
    }
    __syncthreads();
  }
  if (tid == 0) {
    const float vol = sqrtf(r2[0] / (float)W * 252.0f);
    const float mu = r1[0] / (float)W / (float)STEPD * 252.0f;
    out[0] = vol;
    out[1] = mu;
    out[2] = mu / vol;
  }
}

extern "C" void kernel_launch(void* const* d_in, const int* in_sizes, int n_in,
                              void* d_out, int out_size, void* d_ws, size_t ws_size,
                              hipStream_t stream) {
  const float* Y = (const float*)d_in[0];
  const float* a = (const float*)d_in[1];
  const float* logridge = (const float*)d_in[2];
  float* out = (float*)d_out;

  const int n = in_sizes[0] / P;     // 20480 days
  const int K = n / STEPD;           // 1024 blocks
  const int W = K - LAG_W;           // 1000 windows

  float* ws = (float*)d_ws;
  float* wbuf = ws;                  // 2048 floats
  float* e_all = ws + 2048;          // W (<=1024)
  float* s_all = ws + 3072;          // W
  float* cvec = ws + 4096;           // K*128
  float* Gall = ws + 4096 + (size_t)K * P;  // K*128*128

  const size_t need = ((size_t)4096 + (size_t)K * P + (size_t)K * P * P) * sizeof(float);

  weights_kernel<<<1, 512, 0, stream>>>(a, wbuf);
  if (ws_size >= need && (n % STEPD) == 0 && W > 0 && W <= 1024 && (K % SEG) == 0) {
    const int nseg = K / SEG;
    const int nb = (W + 1) >> 1;
    fused_cg_kernel<<<nseg * NCHUNK, 256, 0, stream>>>(Y, wbuf, cvec, Gall, nseg);
    window7_kernel<<<nb, 256, 0, stream>>>(Y, wbuf, logridge, cvec, Gall, e_all, s_all, W, nb);
  } else {
    window_fallback<<<W, 256, 0, stream>>>(Y, wbuf, logridge, e_all, s_all, W);
  }
  final_kernel<<<1, 256, 0, stream>>>(e_all, s_all, out, W);
}

// Round 9
// 123.565 us; speedup vs baseline: 1.8305x; 1.8305x over previous
//
#include <hip/hip_runtime.h>
#include <math.h>

#define P 128
#define T_WIN 480
#define STEPD 20
#define LAG_W 24
#define NITER 16
#define SEG 64

// wbuf layout (floats, 2048 total):
// [0..479]=w_norm  [480..959]=sqrt(w_norm)  [960]=denom  [961]=S
// [962..985]=coef_m=a^(20(23-m))  [986..1005]=sqrt(bw_d)=sqrt(a^(19-d))
// [1024..1174]=pw20[x]=a^(20x)  [1280..1343]=ainvt[k]=a^(-20k), k=0..SEG-1
#define SBW_OFF 986
#define PW20_OFF 1024
#define AINVT_OFF 1280

// ---------------- kernel 0: EWMA weights (fp64, one block) ----------------
__global__ __launch_bounds__(512) void weights_kernel(const float* __restrict__ a,
                                                      float* __restrict__ wbuf) {
  __shared__ double redd[512];
  const int t = threadIdx.x;
  const double la = log((double)a[0]);
  const double u = (t < T_WIN) ? exp((double)(T_WIN - 1 - t) * la) : 0.0;
  redd[t] = u;
  __syncthreads();
  for (int off = 256; off > 0; off >>= 1) {
    if (t < off) redd[t] += redd[t + off];
    __syncthreads();
  }
  const double S = redd[0];
  __syncthreads();
  redd[t] = u * u;
  __syncthreads();
  for (int off = 256; off > 0; off >>= 1) {
    if (t < off) redd[t] += redd[t + off];
    __syncthreads();
  }
  const double Su2 = redd[0];
  if (t < T_WIN) {
    const double wn = u / S * (double)T_WIN;
    wbuf[t] = (float)wn;
    wbuf[T_WIN + t] = (float)sqrt(wn);
  }
  if (t == 0) {
    wbuf[960] = (float)(1.0 - Su2 / (S * S));
    wbuf[961] = (float)S;
  }
  if (t < LAG_W) wbuf[962 + t] = (float)exp((double)(STEPD * (LAG_W - 1 - t)) * la);
  if (t < STEPD) wbuf[SBW_OFF + t] = (float)exp(0.5 * (double)(STEPD - 1 - t) * la);
  if (t < 151) wbuf[PW20_OFF + t] = (float)exp((double)(20 * t) * la);
  if (t < SEG) wbuf[AINVT_OFF + t] = (float)exp(-(double)(20 * t) * la);
}

// ---------------- kernel 1: per-20-day-block outer products ----------------
__global__ __launch_bounds__(256) void cblocks_kernel(const float* __restrict__ Y,
                                                      const float* __restrict__ wbuf,
                                                      float* __restrict__ cvec,
                                                      float* __restrict__ Call, int K) {
  const int k = blockIdx.x;
  const int tid = threadIdx.x;
  const int ti = tid >> 4, tj = tid & 15;
  __shared__ float st[STEPD][P];
  __shared__ float sbwsm[STEPD];
  if (tid < STEPD) sbwsm[tid] = wbuf[SBW_OFF + tid];
  __syncthreads();
  const float* __restrict__ Yb = Y + (size_t)k * STEPD * P;
  for (int i = tid; i < STEPD * P / 4; i += 256) {
    float4 v = ((const float4*)Yb)[i];
    const float sw = sbwsm[i >> 5];
    v.x *= sw; v.y *= sw; v.z *= sw; v.w *= sw;
    ((float4*)&st[0][0])[i] = v;
  }
  __syncthreads();

  float acc[8][8];
#pragma unroll
  for (int u = 0; u < 8; ++u)
#pragma unroll
    for (int v = 0; v < 8; ++v) acc[u][v] = 0.0f;

#pragma unroll 4
  for (int t = 0; t < STEPD; ++t) {
    float af[8], bf[8];
    *(float4*)(af)     = *(const float4*)&st[t][ti * 4];
    *(float4*)(af + 4) = *(const float4*)&st[t][64 + ti * 4];
    *(float4*)(bf)     = *(const float4*)&st[t][tj * 4];
    *(float4*)(bf + 4) = *(const float4*)&st[t][64 + tj * 4];
#pragma unroll
    for (int u = 0; u < 8; ++u)
#pragma unroll
      for (int v = 0; v < 8; ++v) acc[u][v] += af[u] * bf[v];
  }

  float* __restrict__ Ck = Call + (size_t)k * (P * P);
#pragma unroll
  for (int u = 0; u < 8; ++u) {
    const int r = (u < 4) ? (ti * 4 + u) : (64 + ti * 4 + u - 4);
    float4 o0, o1;
    o0.x = acc[u][0]; o0.y = acc[u][1]; o0.z = acc[u][2]; o0.w = acc[u][3];
    o1.x = acc[u][4]; o1.y = acc[u][5]; o1.z = acc[u][6]; o1.w = acc[u][7];
    *(float4*)(Ck + r * P + tj * 4) = o0;
    *(float4*)(Ck + r * P + 64 + tj * 4) = o1;
  }
  if (tid < P) {
    float s = 0.0f;
    for (int t = 0; t < STEPD; ++t) s += sbwsm[t] * st[t][tid];
    cvec[(size_t)k * P + tid] = s;
  }
}

// ---------------- kernel 1.5: segmented weighted prefix scan (in place) ----------------
// G[k] = sum_{i=o_s}^{k} a^(-20(i-o_s)) C_i ; segments of SEG=64 blocks.
// grid: (K/SEG) * 64 blocks of 256; each thread scans one of 16384 elements.
__global__ __launch_bounds__(256) void scan_kernel(float* __restrict__ Call,
                                                   const float* __restrict__ wbuf) {
  __shared__ float asm_[SEG];
  const int tid = threadIdx.x;
  const int seg = blockIdx.x >> 6;
  const int chunk = blockIdx.x & 63;
  if (tid < SEG) asm_[tid] = wbuf[AINVT_OFF + tid];
  __syncthreads();
  const int e = chunk * 256 + tid;
  float* __restrict__ base = Call + ((size_t)seg * SEG) * (P * P) + e;
  float g = 0.0f;
#pragma unroll 4
  for (int k = 0; k < SEG; ++k) {
    const float c = base[(size_t)k * (P * P)];
    g = fmaf(asm_[k], c, g);
    base[(size_t)k * (P * P)] = g;
  }
}

// ---------------- kernel 2: TWO windows per block; batched G loads; dual CG ----------------
__global__ __launch_bounds__(256, 2) void window7_kernel(
    const float* __restrict__ Y, const float* __restrict__ wbuf,
    const float* __restrict__ logridge, const float* __restrict__ cvec,
    const float* __restrict__ Gall, float* __restrict__ e_all,
    float* __restrict__ s_all, int W, int nb) {
  const int bid = blockIdx.x;
  const int q = nb >> 3, rr8 = nb & 7;
  const int xcd = bid & 7, idx = bid >> 3;
  const int wg = ((xcd < rr8) ? (xcd * (q + 1)) : (rr8 * (q + 1) + (xcd - rr8) * q)) + idx;
  const int jA = 2 * wg;
  const int jB = (jA + 1 < W) ? (jA + 1) : jA;

  const int tid = threadIdx.x;
  const int ti = tid >> 4, tj = tid & 15;
  const int lane = tid & 63;
  const int wv = tid >> 6;

  __shared__ float psmA[P], psmB[P];
  __shared__ float ApsmA[P], ApsmB[P];
  __shared__ float vsmA[P], vsmB[P];
  __shared__ float meansmA[P], meansmB[P];
  __shared__ float coefsm[LAG_W];
  __shared__ float pap_waveA[4], pap_waveB[4];
  __shared__ float rs_waveA[4], rs_waveB[4];
  __shared__ float retdA[STEPD], retdB[STEPD];

  if (tid < LAG_W) coefsm[tid] = wbuf[962 + tid];
  __syncthreads();

  const float S = wbuf[961];
  const float denom = wbuf[960];
  const float ridge = expf(logridge[0]);

  int rowi[8], rowoff[8];
#pragma unroll
  for (int u = 0; u < 8; ++u) {
    rowi[u] = (u < 4) ? (ti * 4 + u) : (64 + ti * 4 + u - 4);
    rowoff[u] = rowi[u] * P + tj * 4;
  }

  // ---- G-difference plans ----
  int matsA[3], matsB[3];
  float sclsA[3], sclsB[3];
  int nmA = 0, nmB = 0;
  {
    const int o1 = jA & ~(SEG - 1);
    const int end = jA + 23;
    const int b = o1 + SEG;
    const float pA = wbuf[PW20_OFF + (end - o1)];
    if (end < b) {
      matsA[nmA] = end; sclsA[nmA] = pA; ++nmA;
      if (jA > o1) { matsA[nmA] = jA - 1; sclsA[nmA] = -pA; ++nmA; }
    } else {
      const float pB2 = wbuf[PW20_OFF + (end - b)];
      matsA[nmA] = b - 1; sclsA[nmA] = pA; ++nmA;
      if (jA > o1) { matsA[nmA] = jA - 1; sclsA[nmA] = -pA; ++nmA; }
      matsA[nmA] = end; sclsA[nmA] = pB2; ++nmA;
    }
  }
  {
    const int o1 = jB & ~(SEG - 1);
    const int end = jB + 23;
    const int b = o1 + SEG;
    const float pA = wbuf[PW20_OFF + (end - o1)];
    if (end < b) {
      matsB[nmB] = end; sclsB[nmB] = pA; ++nmB;
      if (jB > o1) { matsB[nmB] = jB - 1; sclsB[nmB] = -pA; ++nmB; }
    } else {
      const float pB2 = wbuf[PW20_OFF + (end - b)];
      matsB[nmB] = b - 1; sclsB[nmB] = pA; ++nmB;
      if (jB > o1) { matsB[nmB] = jB - 1; sclsB[nmB] = -pA; ++nmB; }
      matsB[nmB] = end; sclsB[nmB] = pB2; ++nmB;
    }
  }

  float accA[8][8], accB[8][8];
#pragma unroll
  for (int u = 0; u < 8; ++u)
#pragma unroll
    for (int v = 0; v < 8; ++v) { accA[u][v] = 0.0f; accB[u][v] = 0.0f; }

  auto accum_pair = [&](const float* __restrict__ GmA, float cfA,
                        const float* __restrict__ GmB, float cfB) {
#pragma unroll
    for (int h = 0; h < 2; ++h) {
      float4 ta[8], tb[8];
#pragma unroll
      for (int u = 0; u < 4; ++u) {
        const int uu = h * 4 + u;
        ta[2 * u]     = *(const float4*)(GmA + rowoff[uu]);
        ta[2 * u + 1] = *(const float4*)(GmA + rowoff[uu] + 64);
        tb[2 * u]     = *(const float4*)(GmB + rowoff[uu]);
        tb[2 * u + 1] = *(const float4*)(GmB + rowoff[uu] + 64);
      }
#pragma unroll
      for (int u = 0; u < 4; ++u) {
        const int uu = h * 4 + u;
        accA[uu][0] += cfA * ta[2*u].x;   accA[uu][1] += cfA * ta[2*u].y;
        accA[uu][2] += cfA * ta[2*u].z;   accA[uu][3] += cfA * ta[2*u].w;
        accA[uu][4] += cfA * ta[2*u+1].x; accA[uu][5] += cfA * ta[2*u+1].y;
        accA[uu][6] += cfA * ta[2*u+1].z; accA[uu][7] += cfA * ta[2*u+1].w;
        accB[uu][0] += cfB * tb[2*u].x;   accB[uu][1] += cfB * tb[2*u].y;
        accB[uu][2] += cfB * tb[2*u].z;   accB[uu][3] += cfB * tb[2*u].w;
        accB[uu][4] += cfB * tb[2*u+1].x; accB[uu][5] += cfB * tb[2*u+1].y;
        accB[uu][6] += cfB * tb[2*u+1].z; accB[uu][7] += cfB * tb[2*u+1].w;
      }
    }
  };
  auto accum_one = [&](const float* __restrict__ Gm, float cf, float (*acc)[8]) {
#pragma unroll
    for (int h = 0; h < 2; ++h) {
      float4 ta[8];
#pragma unroll
      for (int u = 0; u < 4; ++u) {
        const int uu = h * 4 + u;
        ta[2 * u]     = *(const float4*)(Gm + rowoff[uu]);
        ta[2 * u + 1] = *(const float4*)(Gm + rowoff[uu] + 64);
      }
#pragma unroll
      for (int u = 0; u < 4; ++u) {
        const int uu = h * 4 + u;
        acc[uu][0] += cf * ta[2*u].x;   acc[uu][1] += cf * ta[2*u].y;
        acc[uu][2] += cf * ta[2*u].z;   acc[uu][3] += cf * ta[2*u].w;
        acc[uu][4] += cf * ta[2*u+1].x; acc[uu][5] += cf * ta[2*u+1].y;
        acc[uu][6] += cf * ta[2*u+1].z; acc[uu][7] += cf * ta[2*u+1].w;
      }
    }
  };

  accum_pair(Gall + (size_t)matsA[0] * (P * P), sclsA[0],
             Gall + (size_t)matsB[0] * (P * P), sclsB[0]);
  for (int m = 1; m < 3; ++m) {
    const bool dA = m < nmA, dB = m < nmB;
    if (dA && dB)
      accum_pair(Gall + (size_t)matsA[m] * (P * P), sclsA[m],
                 Gall + (size_t)matsB[m] * (P * P), sclsB[m]);
    else if (dA)
      accum_one(Gall + (size_t)matsA[m] * (P * P), sclsA[m], accA);
    else if (dB)
      accum_one(Gall + (size_t)matsB[m] * (P * P), sclsB[m], accB);
  }

  // ---- mraw for both windows ----
  if (tid < P) {
    float s = 0.0f;
    for (int m = 0; m < LAG_W; ++m) s += coefsm[m] * cvec[(size_t)(jA + m) * P + tid];
    meansmA[tid] = s;
  } else {
    const int t2 = tid - P;
    float s = 0.0f;
    for (int m = 0; m < LAG_W; ++m) s += coefsm[m] * cvec[(size_t)(jB + m) * P + t2];
    meansmB[t2] = s;
  }
  if (tid < P) { psmA[tid] = 1.0f; psmB[tid] = 1.0f; }
  __syncthreads();

  // ---- M (registers) ----
  {
    const float sc1 = 1.0f / (S * denom);
    const float sc2 = 1.0f / (S * S * denom);
#pragma unroll
    for (int u = 0; u < 8; ++u) {
      const int rr = rowi[u];
      const float mrA = meansmA[rr] * sc2;
      const float mrB = meansmB[rr] * sc2;
#pragma unroll
      for (int v = 0; v < 8; ++v) {
        const int c = (v < 4) ? (tj * 4 + v) : (64 + tj * 4 + (v - 4));
        float mA = accA[u][v] * sc1 - mrA * meansmA[c];
        float mB = accB[u][v] * sc1 - mrB * meansmB[c];
        if (rr == c) { mA += ridge; mB += ridge; }
        accA[u][v] = mA;
        accB[u][v] = mB;
      }
    }
  }

  // ---- dual CG ----
  float xoA = 0.0f, roA = 1.0f, poA = 1.0f, rsA = (float)P;
  float xoB = 0.0f, roB = 1.0f, poB = 1.0f, rsB = (float)P;

  for (int it = 0; it < NITER; ++it) {
    const float4 a0 = *(const float4*)&psmA[tj * 4];
    const float4 a1 = *(const float4*)&psmA[64 + tj * 4];
    const float4 b0 = *(const float4*)&psmB[tj * 4];
    const float4 b1 = *(const float4*)&psmB[64 + tj * 4];
    float pvA[8] = {a0.x, a0.y, a0.z, a0.w, a1.x, a1.y, a1.z, a1.w};
    float pvB[8] = {b0.x, b0.y, b0.z, b0.w, b1.x, b1.y, b1.z, b1.w};
    float apA[8], apB[8];
#pragma unroll
    for (int u = 0; u < 8; ++u) {
      float sA = 0.0f, sB = 0.0f;
#pragma unroll
      for (int v = 0; v < 8; ++v) { sA += accA[u][v] * pvA[v]; sB += accB[u][v] * pvB[v]; }
      apA[u] = sA; apB[u] = sB;
    }
#pragma unroll
    for (int m = 1; m <= 8; m <<= 1) {
#pragma unroll
      for (int u = 0; u < 8; ++u) {
        apA[u] += __shfl_xor(apA[u], m);
        apB[u] += __shfl_xor(apB[u], m);
      }
    }
    if (tj == 0) {
      float papA = 0.0f, papB = 0.0f;
#pragma unroll
      for (int u = 0; u < 8; ++u) {
        ApsmA[rowi[u]] = apA[u]; papA += apA[u] * psmA[rowi[u]];
        ApsmB[rowi[u]] = apB[u]; papB += apB[u] * psmB[rowi[u]];
      }
      papA += __shfl_down(papA, 16); papB += __shfl_down(papB, 16);
      papA += __shfl_down(papA, 32); papB += __shfl_down(papB, 32);
      if (lane == 0) { pap_waveA[wv] = papA; pap_waveB[wv] = papB; }
    }
    __syncthreads();  // B1

    const float papAt = pap_waveA[0] + pap_waveA[1] + pap_waveA[2] + pap_waveA[3];
    const float papBt = pap_waveB[0] + pap_waveB[1] + pap_waveB[2] + pap_waveB[3];
    const float alA = rsA / papAt;
    const float alB = rsB / papBt;
    float rspA = 0.0f, rspB = 0.0f;
    if (tid < P) {
      xoA += alA * poA; roA -= alA * ApsmA[tid]; rspA = roA * roA;
      xoB += alB * poB; roB -= alB * ApsmB[tid]; rspB = roB * roB;
    }
#pragma unroll
    for (int m = 32; m > 0; m >>= 1) {
      rspA += __shfl_down(rspA, m);
      rspB += __shfl_down(rspB, m);
    }
    if (lane == 0) { rs_waveA[wv] = rspA; rs_waveB[wv] = rspB; }
    __syncthreads();  // B2

    const float rsnA = rs_waveA[0] + rs_waveA[1] + rs_waveA[2] + rs_waveA[3];
    const float rsnB = rs_waveB[0] + rs_waveB[1] + rs_waveB[2] + rs_waveB[3];
    const float beA = rsnA / rsA;
    const float beB = rsnB / rsB;
    rsA = rsnA; rsB = rsnB;
    if (tid < P) {
      poA = roA + beA * poA; psmA[tid] = poA;
      poB = roB + beB * poB; psmB[tid] = poB;
    }
    __syncthreads();  // B3
  }

  // ---- publish v, sum(v) ----
  float svA = 0.0f, svB = 0.0f;
  if (tid < P) {
    vsmA[tid] = xoA; vsmB[tid] = xoB;
    svA = xoA; svB = xoB;
  }
#pragma unroll
  for (int m = 32; m > 0; m >>= 1) {
    svA += __shfl_down(svA, m);
    svB += __shfl_down(svB, m);
  }
  if (lane == 0) { rs_waveA[wv] = svA; rs_waveB[wv] = svB; }
  __syncthreads();
  const float sumvA = rs_waveA[0] + rs_waveA[1] + rs_waveA[2] + rs_waveA[3];
  const float sumvB = rs_waveB[0] + rs_waveB[1] + rs_waveB[2] + rs_waveB[3];

  // ---- test returns ----
  const float* __restrict__ YteA = Y + (size_t)(jA + LAG_W) * STEPD * P;
  const float* __restrict__ YteB = Y + (size_t)(jB + LAG_W) * STEPD * P;
  for (int d = wv; d < STEPD; d += 4) {
    float pA = YteA[(size_t)d * P + lane] * vsmA[lane] +
               YteA[(size_t)d * P + 64 + lane] * vsmA[64 + lane];
    float pB = YteB[(size_t)d * P + lane] * vsmB[lane] +
               YteB[(size_t)d * P + 64 + lane] * vsmB[64 + lane];
    for (int off = 32; off > 0; off >>= 1) {
      pA += __shfl_down(pA, off);
      pB += __shfl_down(pB, off);
    }
    if (lane == 0) { retdA[d] = pA; retdB[d] = pB; }
  }
  __syncthreads();

  if (tid == 0) {
    const float invs = 1.0f / sumvA;
    float e = 0.0f, s = 0.0f;
#pragma unroll
    for (int d = 0; d < STEPD; ++d) {
      const float rr = retdA[d] * invs;
      e += rr; s += rr * rr;
    }
    e_all[jA] = e;
    s_all[jA] = s * (1.0f / (float)STEPD);
  } else if (tid == 64) {
    const float invs = 1.0f / sumvB;
    float e = 0.0f, s = 0.0f;
#pragma unroll
    for (int d = 0; d < STEPD; ++d) {
      const float rr = retdB[d] * invs;
      e += rr; s += rr * rr;
    }
    e_all[jB] = e;
    s_all[jB] = s * (1.0f / (float)STEPD);
  }
}

// ---------------- fallback: per-window full recompute ----------------
__global__ __launch_bounds__(256, 2) void window_fallback(
    const float* __restrict__ Y, const float* __restrict__ wbuf,
    const float* __restrict__ logridge, float* __restrict__ e_all,
    float* __restrict__ s_all, int W) {
  const int j = blockIdx.x;
  const int tid = threadIdx.x;
  const int ti = tid >> 4;
  const int tj = tid & 15;

  __shared__ float Msm[P][P + 1];
  __shared__ float wsm[T_WIN];
  __shared__ float swsm[T_WIN];
  __shared__ float meansm[P];
  __shared__ float red[256];
  __shared__ float retd[STEPD];
  __shared__ float zsm[P];
  __shared__ float vsm[P];
  __shared__ float bsm[P];

  float* stage = &Msm[0][0];

  for (int t = tid; t < T_WIN; t += 256) {
    wsm[t] = wbuf[t];
    swsm[t] = wbuf[T_WIN + t];
  }
  if (tid < P) bsm[tid] = 1.0f;
  const float denom = wbuf[960];
  const float ridge = expf(logridge[0]);
  __syncthreads();

  const float* __restrict__ Ywin = Y + (size_t)j * STEPD * P;
  {
    const int col = tid & 127;
    const int half = tid >> 7;
    float m = 0.0f;
    const int t0 = half * (T_WIN / 2), t1 = t0 + T_WIN / 2;
    for (int t = t0; t < t1; ++t) m += wsm[t] * Ywin[(size_t)t * P + col];
    red[tid] = m;
    __syncthreads();
    if (tid < P) meansm[tid] = (red[tid] + red[tid + 128]) * (1.0f / (float)T_WIN);
    __syncthreads();
  }

  float acc[8][8];
#pragma unroll
  for (int u = 0; u < 8; ++u)
#pragma unroll
    for (int v = 0; v < 8; ++v) acc[u][v] = 0.0f;

  for (int c = 0; c < T_WIN / 32; ++c) {
    __syncthreads();
#pragma unroll
    for (int i = 0; i < 4; ++i) {
      const int idx = i * 1024 + tid * 4;
      float4 v = *(const float4*)(Ywin + (size_t)c * 32 * P + idx);
      const float sw = swsm[c * 32 + (idx >> 7)];
      v.x *= sw; v.y *= sw; v.z *= sw; v.w *= sw;
      *(float4*)(stage + idx) = v;
    }
    __syncthreads();
#pragma unroll 4
    for (int t = 0; t < 32; ++t) {
      const float* rowp = stage + t * P;
      float af[8], bf[8];
      *(float4*)(af) = *(const float4*)(rowp + ti * 8);
      *(float4*)(af + 4) = *(const float4*)(rowp + ti * 8 + 4);
      *(float4*)(bf) = *(const float4*)(rowp + tj * 8);
      *(float4*)(bf + 4) = *(const float4*)(rowp + tj * 8 + 4);
#pragma unroll
      for (int u = 0; u < 8; ++u)
#pragma unroll
        for (int v = 0; v < 8; ++v) acc[u][v] += af[u] * bf[v];
    }
  }
  __syncthreads();

  const float invTd = 1.0f / ((float)T_WIN * denom);
#pragma unroll
  for (int u = 0; u < 8; ++u) {
    const int r = ti * 8 + u;
    const float mr = meansm[r];
#pragma unroll
    for (int v = 0; v < 8; ++v) {
      const int cc = tj * 8 + v;
      float m = (acc[u][v] - (float)T_WIN * mr * meansm[cc]) * invTd;
      if (r == cc) m += ridge;
      Msm[r][cc] = m;
    }
  }
  __syncthreads();

  for (int k = 0; k < P; ++k) {
    const float dkk = Msm[k][k];
    const float sq = sqrtf(dkk);
    const float invd = 1.0f / sq;
    if (tid == 0) Msm[k][k] = sq;
    const int i = k + 1 + tid;
    if (i < P) Msm[i][k] *= invd;
    __syncthreads();
    const int nrem = P - 1 - k;
    for (int ii = ti; ii < nrem; ii += 16) {
      const int ri = k + 1 + ii;
      const float Lik = Msm[ri][k];
      for (int jj = tj; jj < nrem; jj += 16) {
        const int cj = k + 1 + jj;
        Msm[ri][cj] -= Lik * Msm[cj][k];
      }
    }
    __syncthreads();
  }

  for (int k = 0; k < P; ++k) {
    const float zk = bsm[k] / Msm[k][k];
    if (tid == 0) zsm[k] = zk;
    const int i = k + 1 + tid;
    if (i < P) bsm[i] -= Msm[i][k] * zk;
    __syncthreads();
  }
  for (int k = P - 1; k >= 0; --k) {
    const float vk = zsm[k] / Msm[k][k];
    if (tid == 0) vsm[k] = vk;
    if (tid < k) zsm[tid] -= Msm[k][tid] * vk;
    __syncthreads();
  }

  red[tid] = (tid < P) ? vsm[tid] : 0.0f;
  __syncthreads();
  for (int off = 128; off > 0; off >>= 1) {
    if (tid < off) red[tid] += red[tid + off];
    __syncthreads();
  }

  const float* __restrict__ Yte = Y + (size_t)(j + LAG_W) * STEPD * P;
  const int wv = tid >> 6;
  const int lane = tid & 63;
  for (int d = wv; d < STEPD; d += 4) {
    float pp = Yte[(size_t)d * P + lane] * vsm[lane] +
               Yte[(size_t)d * P + 64 + lane] * vsm[64 + lane];
    for (int off = 32; off > 0; off >>= 1) pp += __shfl_down(pp, off);
    if (lane == 0) retd[d] = pp;
  }
  __syncthreads();

  if (tid == 0) {
    const float invs = 1.0f / red[0];
    float e = 0.0f, s = 0.0f;
#pragma unroll
    for (int d = 0; d < STEPD; ++d) {
      const float r = retd[d] * invs;
      e += r;
      s += r * r;
    }
    e_all[j] = e;
    s_all[j] = s * (1.0f / (float)STEPD);
  }
}

// ---------------- kernel 3: final reduction ----------------
__global__ __launch_bounds__(256) void final_kernel(const float* __restrict__ e_all,
                                                    const float* __restrict__ s_all,
                                                    float* __restrict__ out, int W) {
  __shared__ float r1[256], r2[256];
  const int tid = threadIdx.x;
  float e = 0.0f, s = 0.0f;
  for (int i = tid; i < W; i += 256) {
    e += e_all[i];
    s += s_all[i];
  }
  r1[tid] = e;
  r2[tid] = s;
  __syncthreads();
  for (int off = 128; off > 0; off >>= 1) {
    if (tid < off) {
      r1[tid] += r1[tid + off];
      r2[tid] += r2[tid + off];
    }
    __syncthreads();
  }
  if (tid == 0) {
    const float vol = sqrtf(r2[0] / (float)W * 252.0f);
    const float mu = r1[0] / (float)W / (float)STEPD * 252.0f;
    out[0] = vol;
    out[1] = mu;
    out[2] = mu / vol;
  }
}

extern "C" void kernel_launch(void* const* d_in, const int* in_sizes, int n_in,
                              void* d_out, int out_size, void* d_ws, size_t ws_size,
                              hipStream_t stream) {
  const float* Y = (const float*)d_in[0];
  const float* a = (const float*)d_in[1];
  const float* logridge = (const float*)d_in[2];
  float* out = (float*)d_out;

  const int n = in_sizes[0] / P;     // 20480 days
  const int K = n / STEPD;           // 1024 blocks
  const int W = K - LAG_W;           // 1000 windows

  float* ws = (float*)d_ws;
  float* wbuf = ws;                  // 2048 floats
  float* e_all = ws + 2048;          // W (<=1024)
  float* s_all = ws + 3072;          // W
  float* cvec = ws + 4096;           // K*128
  float* Gall = ws + 4096 + (size_t)K * P;  // K*128*128 (C, then scanned in place)

  const size_t need = ((size_t)4096 + (size_t)K * P + (size_t)K * P * P) * sizeof(float);

  weights_kernel<<<1, 512, 0, stream>>>(a, wbuf);
  if (ws_size >= need && (n % STEPD) == 0 && W > 0 && W <= 1024 && (K % SEG) == 0) {
    const int nb = (W + 1) >> 1;
    cblocks_kernel<<<K, 256, 0, stream>>>(Y, wbuf, cvec, Gall, K);
    scan_kernel<<<(K / SEG) * 64, 256, 0, stream>>>(Gall, wbuf);
    window7_kernel<<<nb, 256, 0, stream>>>(Y, wbuf, logridge, cvec, Gall, e_all, s_all, W, nb);
  } else {
    window_fallback<<<W, 256, 0, stream>>>(Y, wbuf, logridge, e_all, s_all, W);
  }
  final_kernel<<<1, 256, 0, stream>>>(e_all, s_all, out, W);
}